// Round 4
// baseline (334.340 us; speedup 1.0000x reference)
//
#include <hip/hip_runtime.h>
#include <hip/hip_fp16.h>
#include <math.h>

#define W 512
#define H 512
#define HW (512 * 512)
#define CC 64

typedef float f32x4 __attribute__((ext_vector_type(4)));

// ---------------------------------------------------------------------------
// Kernel 1: channel-wise max + mean over C=64.
// Each thread owns 16 consecutive pixels (4 float4 = 64 B per channel), so a
// wave streams 4 KB contiguous per channel plane. 64 channel streams, strided
// 1 MB apart, nontemporal. Writes interleaved {max, avg} half2 per pixel.
// x: [16,64,512,512] fp32 -> planes: [16, 512*512] half2 (16 MiB total)
// ---------------------------------------------------------------------------
__global__ __launch_bounds__(256) void reduce_kernel(const float* __restrict__ x,
                                                     __half2* __restrict__ planes) {
    const int perB = HW / 4;                      // 65536 float4 per plane
    int t = blockIdx.x * 256 + threadIdx.x;       // 0 .. 262143
    int b = t >> 14;                              // 16384 threads per batch image
    int p = (t & 16383) * 4;                      // float4 index within plane

    const f32x4* xb = reinterpret_cast<const f32x4*>(x) + (size_t)b * CC * perB + p;

    f32x4 mx[4], sm[4];
    #pragma unroll
    for (int j = 0; j < 4; ++j) {
        f32x4 v = __builtin_nontemporal_load(xb + j);
        mx[j] = v;
        sm[j] = v;
    }

    #pragma unroll 4
    for (int c = 1; c < CC; ++c) {
        const f32x4* q = xb + (size_t)c * perB;
        f32x4 u[4];
        #pragma unroll
        for (int j = 0; j < 4; ++j) u[j] = __builtin_nontemporal_load(q + j);
        #pragma unroll
        for (int j = 0; j < 4; ++j) {
            mx[j].x = fmaxf(mx[j].x, u[j].x);  sm[j].x += u[j].x;
            mx[j].y = fmaxf(mx[j].y, u[j].y);  sm[j].y += u[j].y;
            mx[j].z = fmaxf(mx[j].z, u[j].z);  sm[j].z += u[j].z;
            mx[j].w = fmaxf(mx[j].w, u[j].w);  sm[j].w += u[j].w;
        }
    }

    const float inv = 1.0f / (float)CC;
    uint4* dst = reinterpret_cast<uint4*>(planes + (size_t)b * HW + p * 4);
    #pragma unroll
    for (int j = 0; j < 4; ++j) {
        __half2 h[4];
        h[0] = __floats2half2_rn(mx[j].x, sm[j].x * inv);
        h[1] = __floats2half2_rn(mx[j].y, sm[j].y * inv);
        h[2] = __floats2half2_rn(mx[j].z, sm[j].z * inv);
        h[3] = __floats2half2_rn(mx[j].w, sm[j].w * inv);
        dst[j] = *reinterpret_cast<uint4*>(&h[0]);
    }
}

// ---------------------------------------------------------------------------
// Kernel 2: 7x7 conv (pad 3) over interleaved {max,avg} half2 planes + sigmoid.
// Block = (32,8); 32x32 output tile; 38x38 halo staged in LDS as float2.
// Each thread computes 4 consecutive rows (register row-blocking).
// ---------------------------------------------------------------------------
__global__ __launch_bounds__(256) void conv_kernel(const __half2* __restrict__ planes,
                                                   const float* __restrict__ wgt,
                                                   float* __restrict__ out) {
    __shared__ float2 sm[38][40];

    const int b   = blockIdx.z;
    const int th0 = blockIdx.y * 32;
    const int tw0 = blockIdx.x * 32;
    const int tid = threadIdx.y * 32 + threadIdx.x;

    const __half2* pb = planes + (size_t)b * HW;

    for (int i = tid; i < 38 * 38; i += 256) {
        int r = i / 38, c = i - r * 38;
        int h = th0 + r - 3;
        int w = tw0 + c - 3;
        float2 v = make_float2(0.0f, 0.0f);
        if (h >= 0 && h < H && w >= 0 && w < W) {
            v = __half22float2(pb[h * W + w]);
        }
        sm[r][c] = v;
    }

    float wm[49], wa[49];
    #pragma unroll
    for (int i = 0; i < 49; ++i) {
        wm[i] = wgt[i];
        wa[i] = wgt[49 + i];
    }

    __syncthreads();

    const int tx = threadIdx.x;
    const int ty = threadIdx.y;

    float acc0 = 0.f, acc1 = 0.f, acc2 = 0.f, acc3 = 0.f;
    #pragma unroll
    for (int r = 0; r < 10; ++r) {
        #pragma unroll
        for (int kw = 0; kw < 7; ++kw) {
            float2 v = sm[4 * ty + r][tx + kw];
            #pragma unroll
            for (int k = 0; k < 4; ++k) {
                int kh = r - k;
                if (kh >= 0 && kh < 7) {
                    float a = (k == 0) ? acc0 : (k == 1) ? acc1 : (k == 2) ? acc2 : acc3;
                    a = fmaf(v.x, wm[kh * 7 + kw], a);
                    a = fmaf(v.y, wa[kh * 7 + kw], a);
                    if (k == 0) acc0 = a; else if (k == 1) acc1 = a; else if (k == 2) acc2 = a; else acc3 = a;
                }
            }
        }
    }

    float* ob = out + (size_t)b * HW + (size_t)tw0 + tx;
    {
        int h = th0 + 4 * ty;
        ob[(h + 0) * W] = 1.0f / (1.0f + __expf(-acc0));
        ob[(h + 1) * W] = 1.0f / (1.0f + __expf(-acc1));
        ob[(h + 2) * W] = 1.0f / (1.0f + __expf(-acc2));
        ob[(h + 3) * W] = 1.0f / (1.0f + __expf(-acc3));
    }
}

extern "C" void kernel_launch(void* const* d_in, const int* in_sizes, int n_in,
                              void* d_out, int out_size, void* d_ws, size_t ws_size,
                              hipStream_t stream) {
    const float* x   = (const float*)d_in[0];   // [16,64,512,512]
    const float* wgt = (const float*)d_in[1];   // [1,2,7,7]
    float* out = (float*)d_out;                 // [16,1,512,512]
    __half2* planes = (__half2*)d_ws;           // [16, 512*512] half2 (16 MiB)

    // Pass 1: channel reduce. 262144 threads / 256 = 1024 blocks.
    reduce_kernel<<<dim3(1024), dim3(256), 0, stream>>>(x, planes);

    // Pass 2: conv + sigmoid. 16x16 tiles x 16 batches.
    conv_kernel<<<dim3(16, 16, 16), dim3(32, 8), 0, stream>>>(planes, wgt, out);
}

// Round 5
// 208.475 us; speedup vs baseline: 1.6037x; 1.6037x over previous
//
#include <hip/hip_runtime.h>
#include <hip/hip_fp16.h>
#include <math.h>

#define W 512
#define H 512
#define HW (512 * 512)
#define CC 64

typedef float f32x4 __attribute__((ext_vector_type(4)));

// ---------------------------------------------------------------------------
// Kernel 1: channel-wise max + mean over C=64.
// Each block of 256 threads owns 512 consecutive float4 (8 KB) of each
// channel plane; each thread processes float4 [tid] and [tid+256] -> both
// load streams are perfectly coalesced (16 B/lane contiguous). 64 channel
// streams strided 1 MB, nontemporal. Writes interleaved {max,avg} half2.
// x: [16,64,512,512] fp32 -> planes: [16, 512*512] half2 (16 MiB total)
// ---------------------------------------------------------------------------
__global__ __launch_bounds__(256) void reduce_kernel(const float* __restrict__ x,
                                                     __half2* __restrict__ planes) {
    const int perB = HW / 4;                      // 65536 float4 per plane
    const int tid  = threadIdx.x;
    const int blk  = blockIdx.x & 127;            // 128 blocks per image
    const int b    = blockIdx.x >> 7;
    const int base = blk * 512;                   // block's float4 base in plane

    const f32x4* xb = reinterpret_cast<const f32x4*>(x)
                    + (size_t)b * CC * perB + base + tid;

    f32x4 mx0 = __builtin_nontemporal_load(xb);
    f32x4 mx1 = __builtin_nontemporal_load(xb + 256);
    f32x4 sm0 = mx0, sm1 = mx1;

    #pragma unroll 8
    for (int c = 1; c < CC; ++c) {
        const f32x4* q = xb + (size_t)c * perB;
        f32x4 a  = __builtin_nontemporal_load(q);
        f32x4 bq = __builtin_nontemporal_load(q + 256);
        mx0.x = fmaxf(mx0.x, a.x);  sm0.x += a.x;
        mx0.y = fmaxf(mx0.y, a.y);  sm0.y += a.y;
        mx0.z = fmaxf(mx0.z, a.z);  sm0.z += a.z;
        mx0.w = fmaxf(mx0.w, a.w);  sm0.w += a.w;
        mx1.x = fmaxf(mx1.x, bq.x); sm1.x += bq.x;
        mx1.y = fmaxf(mx1.y, bq.y); sm1.y += bq.y;
        mx1.z = fmaxf(mx1.z, bq.z); sm1.z += bq.z;
        mx1.w = fmaxf(mx1.w, bq.w); sm1.w += bq.w;
    }

    const float inv = 1.0f / (float)CC;
    __half2 h0[4], h1[4];
    h0[0] = __floats2half2_rn(mx0.x, sm0.x * inv);
    h0[1] = __floats2half2_rn(mx0.y, sm0.y * inv);
    h0[2] = __floats2half2_rn(mx0.z, sm0.z * inv);
    h0[3] = __floats2half2_rn(mx0.w, sm0.w * inv);
    h1[0] = __floats2half2_rn(mx1.x, sm1.x * inv);
    h1[1] = __floats2half2_rn(mx1.y, sm1.y * inv);
    h1[2] = __floats2half2_rn(mx1.z, sm1.z * inv);
    h1[3] = __floats2half2_rn(mx1.w, sm1.w * inv);

    // one uint4 (16 B) holds the 4 half2 pixels of one float4
    uint4* dst = reinterpret_cast<uint4*>(planes + (size_t)b * HW) + base + tid;
    dst[0]   = *reinterpret_cast<uint4*>(&h0[0]);
    dst[256] = *reinterpret_cast<uint4*>(&h1[0]);
}

// ---------------------------------------------------------------------------
// Kernel 2: 7x7 conv (pad 3) over interleaved {max,avg} half2 planes + sigmoid.
// Block = (32,8); 32x32 output tile; 38x38 halo staged in LDS as float2.
// Each thread computes 4 consecutive rows (register row-blocking).
// ---------------------------------------------------------------------------
__global__ __launch_bounds__(256) void conv_kernel(const __half2* __restrict__ planes,
                                                   const float* __restrict__ wgt,
                                                   float* __restrict__ out) {
    __shared__ float2 sm[38][40];

    const int b   = blockIdx.z;
    const int th0 = blockIdx.y * 32;
    const int tw0 = blockIdx.x * 32;
    const int tid = threadIdx.y * 32 + threadIdx.x;

    const __half2* pb = planes + (size_t)b * HW;

    for (int i = tid; i < 38 * 38; i += 256) {
        int r = i / 38, c = i - r * 38;
        int h = th0 + r - 3;
        int w = tw0 + c - 3;
        float2 v = make_float2(0.0f, 0.0f);
        if (h >= 0 && h < H && w >= 0 && w < W) {
            v = __half22float2(pb[h * W + w]);
        }
        sm[r][c] = v;
    }

    float wm[49], wa[49];
    #pragma unroll
    for (int i = 0; i < 49; ++i) {
        wm[i] = wgt[i];
        wa[i] = wgt[49 + i];
    }

    __syncthreads();

    const int tx = threadIdx.x;
    const int ty = threadIdx.y;

    float acc0 = 0.f, acc1 = 0.f, acc2 = 0.f, acc3 = 0.f;
    #pragma unroll
    for (int r = 0; r < 10; ++r) {
        #pragma unroll
        for (int kw = 0; kw < 7; ++kw) {
            float2 v = sm[4 * ty + r][tx + kw];
            #pragma unroll
            for (int k = 0; k < 4; ++k) {
                int kh = r - k;
                if (kh >= 0 && kh < 7) {
                    float a = (k == 0) ? acc0 : (k == 1) ? acc1 : (k == 2) ? acc2 : acc3;
                    a = fmaf(v.x, wm[kh * 7 + kw], a);
                    a = fmaf(v.y, wa[kh * 7 + kw], a);
                    if (k == 0) acc0 = a; else if (k == 1) acc1 = a; else if (k == 2) acc2 = a; else acc3 = a;
                }
            }
        }
    }

    float* ob = out + (size_t)b * HW + (size_t)tw0 + tx;
    {
        int h = th0 + 4 * ty;
        ob[(h + 0) * W] = 1.0f / (1.0f + __expf(-acc0));
        ob[(h + 1) * W] = 1.0f / (1.0f + __expf(-acc1));
        ob[(h + 2) * W] = 1.0f / (1.0f + __expf(-acc2));
        ob[(h + 3) * W] = 1.0f / (1.0f + __expf(-acc3));
    }
}

extern "C" void kernel_launch(void* const* d_in, const int* in_sizes, int n_in,
                              void* d_out, int out_size, void* d_ws, size_t ws_size,
                              hipStream_t stream) {
    const float* x   = (const float*)d_in[0];   // [16,64,512,512]
    const float* wgt = (const float*)d_in[1];   // [1,2,7,7]
    float* out = (float*)d_out;                 // [16,1,512,512]
    __half2* planes = (__half2*)d_ws;           // [16, 512*512] half2 (16 MiB)

    // Pass 1: channel reduce. 2048 blocks x 256 threads.
    reduce_kernel<<<dim3(2048), dim3(256), 0, stream>>>(x, planes);

    // Pass 2: conv + sigmoid. 16x16 tiles x 16 batches.
    conv_kernel<<<dim3(16, 16, 16), dim3(32, 8), 0, stream>>>(planes, wgt, out);
}

// Round 6
// 201.194 us; speedup vs baseline: 1.6618x; 1.0362x over previous
//
#include <hip/hip_runtime.h>
#include <hip/hip_fp16.h>
#include <math.h>

#define W 512
#define H 512
#define HW (512 * 512)
#define CC 64

typedef float f32x4 __attribute__((ext_vector_type(4)));

// ---------------------------------------------------------------------------
// Kernel 1: channel-wise max + mean over C=64.
// Each block of 256 threads owns 1024 consecutive float4 (16 KB) per channel
// plane; each thread processes float4 [tid+0/256/512/768] -> all four load
// streams perfectly coalesced (16 B/lane). 64 channel streams strided 1 MB,
// nontemporal reads. Writes interleaved {max,avg} half2 (L2-resident for k2).
// x: [16,64,512,512] fp32 -> planes: [16, 512*512] half2 (16 MiB total)
// ---------------------------------------------------------------------------
__global__ __launch_bounds__(256) void reduce_kernel(const float* __restrict__ x,
                                                     __half2* __restrict__ planes) {
    const int perB = HW / 4;                      // 65536 float4 per plane
    const int tid  = threadIdx.x;
    const int blk  = blockIdx.x & 63;             // 64 blocks per image
    const int b    = blockIdx.x >> 6;
    const int base = blk * 1024;                  // block's float4 base in plane

    const f32x4* xb = reinterpret_cast<const f32x4*>(x)
                    + (size_t)b * CC * perB + base + tid;

    f32x4 mx[4], sm[4];
    #pragma unroll
    for (int j = 0; j < 4; ++j) {
        f32x4 v = __builtin_nontemporal_load(xb + j * 256);
        mx[j] = v;
        sm[j] = v;
    }

    #pragma unroll 4
    for (int c = 1; c < CC; ++c) {
        const f32x4* q = xb + (size_t)c * perB;
        f32x4 u[4];
        #pragma unroll
        for (int j = 0; j < 4; ++j) u[j] = __builtin_nontemporal_load(q + j * 256);
        #pragma unroll
        for (int j = 0; j < 4; ++j) {
            mx[j].x = fmaxf(mx[j].x, u[j].x);  sm[j].x += u[j].x;
            mx[j].y = fmaxf(mx[j].y, u[j].y);  sm[j].y += u[j].y;
            mx[j].z = fmaxf(mx[j].z, u[j].z);  sm[j].z += u[j].z;
            mx[j].w = fmaxf(mx[j].w, u[j].w);  sm[j].w += u[j].w;
        }
    }

    const float inv = 1.0f / (float)CC;
    uint4* dst = reinterpret_cast<uint4*>(planes + (size_t)b * HW) + base + tid;
    #pragma unroll
    for (int j = 0; j < 4; ++j) {
        __half2 h[4];
        h[0] = __floats2half2_rn(mx[j].x, sm[j].x * inv);
        h[1] = __floats2half2_rn(mx[j].y, sm[j].y * inv);
        h[2] = __floats2half2_rn(mx[j].z, sm[j].z * inv);
        h[3] = __floats2half2_rn(mx[j].w, sm[j].w * inv);
        dst[j * 256] = *reinterpret_cast<uint4*>(&h[0]);
    }
}

// ---------------------------------------------------------------------------
// Kernel 2: 7x7 conv (pad 3) over interleaved {max,avg} half2 planes + sigmoid.
// Block = (32,8); 32x32 output tile; 38x38 halo staged in LDS as float2.
// Each thread computes 4 consecutive rows (register row-blocking).
// ---------------------------------------------------------------------------
__global__ __launch_bounds__(256) void conv_kernel(const __half2* __restrict__ planes,
                                                   const float* __restrict__ wgt,
                                                   float* __restrict__ out) {
    __shared__ float2 sm[38][40];

    const int b   = blockIdx.z;
    const int th0 = blockIdx.y * 32;
    const int tw0 = blockIdx.x * 32;
    const int tid = threadIdx.y * 32 + threadIdx.x;

    const __half2* pb = planes + (size_t)b * HW;

    for (int i = tid; i < 38 * 38; i += 256) {
        int r = i / 38, c = i - r * 38;
        int h = th0 + r - 3;
        int w = tw0 + c - 3;
        float2 v = make_float2(0.0f, 0.0f);
        if (h >= 0 && h < H && w >= 0 && w < W) {
            v = __half22float2(pb[h * W + w]);
        }
        sm[r][c] = v;
    }

    float wm[49], wa[49];
    #pragma unroll
    for (int i = 0; i < 49; ++i) {
        wm[i] = wgt[i];
        wa[i] = wgt[49 + i];
    }

    __syncthreads();

    const int tx = threadIdx.x;
    const int ty = threadIdx.y;

    float acc0 = 0.f, acc1 = 0.f, acc2 = 0.f, acc3 = 0.f;
    #pragma unroll
    for (int r = 0; r < 10; ++r) {
        #pragma unroll
        for (int kw = 0; kw < 7; ++kw) {
            float2 v = sm[4 * ty + r][tx + kw];
            #pragma unroll
            for (int k = 0; k < 4; ++k) {
                int kh = r - k;
                if (kh >= 0 && kh < 7) {
                    float a = (k == 0) ? acc0 : (k == 1) ? acc1 : (k == 2) ? acc2 : acc3;
                    a = fmaf(v.x, wm[kh * 7 + kw], a);
                    a = fmaf(v.y, wa[kh * 7 + kw], a);
                    if (k == 0) acc0 = a; else if (k == 1) acc1 = a; else if (k == 2) acc2 = a; else acc3 = a;
                }
            }
        }
    }

    float* ob = out + (size_t)b * HW + (size_t)tw0 + tx;
    {
        int h = th0 + 4 * ty;
        ob[(h + 0) * W] = 1.0f / (1.0f + __expf(-acc0));
        ob[(h + 1) * W] = 1.0f / (1.0f + __expf(-acc1));
        ob[(h + 2) * W] = 1.0f / (1.0f + __expf(-acc2));
        ob[(h + 3) * W] = 1.0f / (1.0f + __expf(-acc3));
    }
}

extern "C" void kernel_launch(void* const* d_in, const int* in_sizes, int n_in,
                              void* d_out, int out_size, void* d_ws, size_t ws_size,
                              hipStream_t stream) {
    const float* x   = (const float*)d_in[0];   // [16,64,512,512]
    const float* wgt = (const float*)d_in[1];   // [1,2,7,7]
    float* out = (float*)d_out;                 // [16,1,512,512]
    __half2* planes = (__half2*)d_ws;           // [16, 512*512] half2 (16 MiB)

    // Pass 1: channel reduce. 1024 blocks x 256 threads.
    reduce_kernel<<<dim3(1024), dim3(256), 0, stream>>>(x, planes);

    // Pass 2: conv + sigmoid. 16x16 tiles x 16 batches.
    conv_kernel<<<dim3(16, 16, 16), dim3(32, 8), 0, stream>>>(planes, wgt, out);
}

// Round 7
// 189.814 us; speedup vs baseline: 1.7614x; 1.0600x over previous
//
#include <hip/hip_runtime.h>
#include <hip/hip_fp16.h>
#include <math.h>

#define W 512
#define H 512
#define HW (512 * 512)
#define CC 64

typedef float f32x4 __attribute__((ext_vector_type(4)));

// ---------------------------------------------------------------------------
// Kernel 1: channel-wise max + mean over C=64.
// Each block of 256 threads owns 2048 consecutive float4 (32 KB) per channel
// plane; each thread processes float4 [tid + j*256], j=0..7 -> all eight load
// streams perfectly coalesced (16 B/lane). 64 channel streams strided 1 MB,
// nontemporal reads. Writes interleaved {max,avg} half2 (L2-resident for k2).
// x: [16,64,512,512] fp32 -> planes: [16, 512*512] half2 (16 MiB total)
// ---------------------------------------------------------------------------
__global__ __launch_bounds__(256) void reduce_kernel(const float* __restrict__ x,
                                                     __half2* __restrict__ planes) {
    const int perB = HW / 4;                      // 65536 float4 per plane
    const int tid  = threadIdx.x;
    const int blk  = blockIdx.x & 31;             // 32 blocks per image
    const int b    = blockIdx.x >> 5;
    const int base = blk * 2048;                  // block's float4 base in plane

    const f32x4* xb = reinterpret_cast<const f32x4*>(x)
                    + (size_t)b * CC * perB + base + tid;

    f32x4 mx[8], sm[8];
    #pragma unroll
    for (int j = 0; j < 8; ++j) {
        f32x4 v = __builtin_nontemporal_load(xb + j * 256);
        mx[j] = v;
        sm[j] = v;
    }

    #pragma unroll 2
    for (int c = 1; c < CC; ++c) {
        const f32x4* q = xb + (size_t)c * perB;
        f32x4 u[8];
        #pragma unroll
        for (int j = 0; j < 8; ++j) u[j] = __builtin_nontemporal_load(q + j * 256);
        #pragma unroll
        for (int j = 0; j < 8; ++j) {
            mx[j].x = fmaxf(mx[j].x, u[j].x);  sm[j].x += u[j].x;
            mx[j].y = fmaxf(mx[j].y, u[j].y);  sm[j].y += u[j].y;
            mx[j].z = fmaxf(mx[j].z, u[j].z);  sm[j].z += u[j].z;
            mx[j].w = fmaxf(mx[j].w, u[j].w);  sm[j].w += u[j].w;
        }
    }

    const float inv = 1.0f / (float)CC;
    uint4* dst = reinterpret_cast<uint4*>(planes + (size_t)b * HW) + base + tid;
    #pragma unroll
    for (int j = 0; j < 8; ++j) {
        __half2 h[4];
        h[0] = __floats2half2_rn(mx[j].x, sm[j].x * inv);
        h[1] = __floats2half2_rn(mx[j].y, sm[j].y * inv);
        h[2] = __floats2half2_rn(mx[j].z, sm[j].z * inv);
        h[3] = __floats2half2_rn(mx[j].w, sm[j].w * inv);
        dst[j * 256] = *reinterpret_cast<uint4*>(&h[0]);
    }
}

// ---------------------------------------------------------------------------
// Kernel 2: 7x7 conv (pad 3) over interleaved {max,avg} half2 planes + sigmoid.
// Block = (32,8); 32x32 output tile; 38x38 halo staged in LDS as float2.
// Each thread computes 4 consecutive rows (register row-blocking).
// ---------------------------------------------------------------------------
__global__ __launch_bounds__(256) void conv_kernel(const __half2* __restrict__ planes,
                                                   const float* __restrict__ wgt,
                                                   float* __restrict__ out) {
    __shared__ float2 sm[38][40];

    const int b   = blockIdx.z;
    const int th0 = blockIdx.y * 32;
    const int tw0 = blockIdx.x * 32;
    const int tid = threadIdx.y * 32 + threadIdx.x;

    const __half2* pb = planes + (size_t)b * HW;

    for (int i = tid; i < 38 * 38; i += 256) {
        int r = i / 38, c = i - r * 38;
        int h = th0 + r - 3;
        int w = tw0 + c - 3;
        float2 v = make_float2(0.0f, 0.0f);
        if (h >= 0 && h < H && w >= 0 && w < W) {
            v = __half22float2(pb[h * W + w]);
        }
        sm[r][c] = v;
    }

    float wm[49], wa[49];
    #pragma unroll
    for (int i = 0; i < 49; ++i) {
        wm[i] = wgt[i];
        wa[i] = wgt[49 + i];
    }

    __syncthreads();

    const int tx = threadIdx.x;
    const int ty = threadIdx.y;

    float acc0 = 0.f, acc1 = 0.f, acc2 = 0.f, acc3 = 0.f;
    #pragma unroll
    for (int r = 0; r < 10; ++r) {
        #pragma unroll
        for (int kw = 0; kw < 7; ++kw) {
            float2 v = sm[4 * ty + r][tx + kw];
            #pragma unroll
            for (int k = 0; k < 4; ++k) {
                int kh = r - k;
                if (kh >= 0 && kh < 7) {
                    float a = (k == 0) ? acc0 : (k == 1) ? acc1 : (k == 2) ? acc2 : acc3;
                    a = fmaf(v.x, wm[kh * 7 + kw], a);
                    a = fmaf(v.y, wa[kh * 7 + kw], a);
                    if (k == 0) acc0 = a; else if (k == 1) acc1 = a; else if (k == 2) acc2 = a; else acc3 = a;
                }
            }
        }
    }

    float* ob = out + (size_t)b * HW + (size_t)tw0 + tx;
    {
        int h = th0 + 4 * ty;
        ob[(h + 0) * W] = 1.0f / (1.0f + __expf(-acc0));
        ob[(h + 1) * W] = 1.0f / (1.0f + __expf(-acc1));
        ob[(h + 2) * W] = 1.0f / (1.0f + __expf(-acc2));
        ob[(h + 3) * W] = 1.0f / (1.0f + __expf(-acc3));
    }
}

extern "C" void kernel_launch(void* const* d_in, const int* in_sizes, int n_in,
                              void* d_out, int out_size, void* d_ws, size_t ws_size,
                              hipStream_t stream) {
    const float* x   = (const float*)d_in[0];   // [16,64,512,512]
    const float* wgt = (const float*)d_in[1];   // [1,2,7,7]
    float* out = (float*)d_out;                 // [16,1,512,512]
    __half2* planes = (__half2*)d_ws;           // [16, 512*512] half2 (16 MiB)

    // Pass 1: channel reduce. 512 blocks x 256 threads (exactly 2 blocks/CU).
    reduce_kernel<<<dim3(512), dim3(256), 0, stream>>>(x, planes);

    // Pass 2: conv + sigmoid. 16x16 tiles x 16 batches.
    conv_kernel<<<dim3(16, 16, 16), dim3(32, 8), 0, stream>>>(planes, wgt, out);
}